// Round 8
// baseline (419.544 us; speedup 1.0000x reference)
//
#include <hip/hip_runtime.h>
#include <hip/hip_fp16.h>
#include <hip/hip_cooperative_groups.h>

// DCell forward, MI355X (gfx950). All inputs/outputs fp32.
// R20: cooperative fusion of pack + gemm32 (one dispatch, grid.sync between).
// History: R15/R17 killed occupancy theory; R16 killed page-locality; R18
// (-7us) removed chain stalls; R19 (-1us) proved traffic re-routing is
// zero-sum -> pipeline cost = serial sum of dispatches, each above traffic
// floor. R20 removes the pack->gemm32 dispatch boundary (pack tail + launch
// gap) via hipLaunchCooperativeKernel: 512 blocks (2/CU co-resident by LDS),
// phase1 = grid-stride sequential ballot pack of ALL strata (2048 waves x
// 21 iters x 16 rows, coalesced 256B/wave-instr), grid.sync(), phase2 =
// gemm32 body (fused s3+s2, 40KB LDS h3 tile, batched W staging, block BN).
// Ballot bit order and all arithmetic identical -> absmax unchanged.
// ws: [gTb3 | gTb2 | gTb1 | h2 fp16 | h1 fp16 | z0p] ~18 MB.

namespace cg = cooperative_groups;

#define DEV static __device__ __forceinline__

constexpr int B_  = 256, G_ = 64, D_ = 20;
constexpr int T3_ = 2048, T2_ = 512, T1_ = 128;
constexpr float EPS_ = 1e-5f;

typedef unsigned char u8;
typedef unsigned long long u64;

constexpr size_t OFF_GTB3 = 0;
constexpr size_t SZ_GTB3 = (size_t)T3_ * B_ * 8;
constexpr size_t OFF_GTB2 = OFF_GTB3 + SZ_GTB3;
constexpr size_t SZ_GTB2 = (size_t)T2_ * B_ * 8;
constexpr size_t OFF_GTB1 = OFF_GTB2 + SZ_GTB2;
constexpr size_t SZ_GTB1 = (size_t)T1_ * B_ * 8;
constexpr size_t OFF_H2B = OFF_GTB1 + SZ_GTB1;
constexpr size_t SZ_H2 = (size_t)T2_ * B_ * D_ * 2;
constexpr size_t OFF_H1B = OFF_H2B + SZ_H2;
constexpr size_t SZ_H1 = (size_t)T1_ * B_ * D_ * 2;
constexpr size_t OFF_Z0B = OFF_H1B + SZ_H1;

typedef _Float16 half8_t __attribute__((ext_vector_type(8)));
typedef float f32x4 __attribute__((ext_vector_type(4)));

DEV half8_t as_h8(uint4 u) {
    union { uint4 u4; half8_t h; } c; c.u4 = u; return c.h;
}

// 8 gene BITS -> half8 {0.0h,1.0h}. Exact (no carries: operands are 0/1).
DEV half8_t bits8_to_h8(uint byte) {
    uint4 r;
    r.x = ((byte & 1u)        | ((byte & 2u)   << 15)) * 0x3C00u;
    r.y = (((byte >> 2) & 1u) | ((byte & 8u)   << 13)) * 0x3C00u;
    r.z = (((byte >> 4) & 1u) | ((byte & 32u)  << 11)) * 0x3C00u;
    r.w = (((byte >> 6) & 1u) | ((byte & 128u) << 9))  * 0x3C00u;
    return as_h8(r);
}

DEV float fast_tanh(float x) {
    float e = __expf(2.0f * x);
    return fmaf(-2.0f, __builtin_amdgcn_rcpf(e + 1.0f), 1.0f);
}

// ---- cooperative: phase1 pack all strata, grid.sync, phase2 fused s3+s2 ----
__global__ __launch_bounds__(256, 2) void k_packgemm32(
        const float* __restrict__ genes3f, const float* __restrict__ genes2f,
        const float* __restrict__ genes1f,
        u64* __restrict__ gTb3, u64* __restrict__ gTb2, u64* __restrict__ gTb1,
        const float* __restrict__ W3, const float* __restrict__ g3,
        const float* __restrict__ be3,
        const float* __restrict__ W2, const float* __restrict__ g2,
        const float* __restrict__ be2, __half* __restrict__ h2out) {
    constexpr int STRB3 = 72, STRB2 = 200;
    __shared__ __align__(16) __half h3loc[4 * B_ * D_ + 16];  // +pad for A-overrun
    __shared__ __align__(16) __half WT3[2][32 * STRB3];
    __shared__ __align__(16) __half WT2[32 * STRB2];
    __shared__ u64 gmask[5][B_];
    __shared__ float sredb[2][4][16], qredb[2][4][16];
    __shared__ float gv3[4 * D_], bev3[4 * D_], gv2[D_], bev2[D_];

    const int t = blockIdx.x, tid = threadIdx.x;
    const int w = tid >> 6, lane = tid & 63;

    // ---- phase 1: grid-stride sequential ballot pack (all 3 strata) ----
    // 2048 waves x 21 iters x 16 rows = 688128 rows; 256B/wave-instr reads.
    {
        const int gwave = blockIdx.x * 4 + w;      // 0..2047
        constexpr int R3 = B_ * T3_;               // 524288 (mult of 16)
        constexpr int R2 = B_ * T2_;               // 131072 (mult of 16)
#pragma unroll 2
        for (int it = 0; it < 21; ++it) {
            int R0 = (gwave + it * 2048) * 16;
            const float* src; u64* dst; int shift; int Rb;
            if (R0 < R3)           { src = genes3f; dst = gTb3; shift = 11; Rb = R0; }
            else if (R0 < R3 + R2) { src = genes2f; dst = gTb2; shift = 9;  Rb = R0 - R3; }
            else                   { src = genes1f; dst = gTb1; shift = 7;  Rb = R0 - R3 - R2; }
            const float* p = src + (size_t)Rb * G_ + lane;
            float x[16];
#pragma unroll
            for (int r = 0; r < 16; ++r) x[r] = p[(size_t)r * G_];
            u64 m = 0;
#pragma unroll
            for (int r = 0; r < 16; ++r) {
                u64 mm = __ballot(x[r] != 0.0f);
                if (lane == r) m = mm;
            }
            if (lane < 16) {
                const int R = Rb + lane;
                const int b = R >> shift, tt = R - (b << shift);
                dst[(size_t)tt * B_ + b] = m;
            }
        }
    }
    cg::this_grid().sync();    // all masks visible, device scope

    // ---- phase 2: fused strata 3+2 GEMM (block = s2 term t) ----
    // load masks (5 coalesced 2KB segments, all in flight)
    u64 mreg[5];
#pragma unroll
    for (int c = 0; c < 4; ++c)
        mreg[c] = gTb3[(size_t)(4 * t + c) * B_ + tid];
    mreg[4] = gTb2[(size_t)t * B_ + tid];

    // zero WT2 (k-pad rows must be 0) + h3loc tail pad while masks in flight
    {
        uint* WTu = (uint*)WT2;
        for (int j = tid; j < 32 * STRB2 / 2; j += 256) WTu[j] = 0;
        if (tid < 16) h3loc[4 * B_ * D_ + tid] = __half(0.0f);
    }
#pragma unroll
    for (int s = 0; s < 5; ++s) gmask[s][tid] = mreg[s];
    __syncthreads();

    // stage W2 (k-mapped, batched loads), W3 child0, BN params
    if (tid < 4 * D_) {
        gv3[tid] = g3[(size_t)(4 * t) * D_ + tid];
        bev3[tid] = be3[(size_t)(4 * t) * D_ + tid];
    } else if (tid < 5 * D_) {
        gv2[tid - 4 * D_] = g2[(size_t)t * D_ + (tid - 4 * D_)];
        bev2[tid - 4 * D_] = be2[(size_t)t * D_ + (tid - 4 * D_)];
    }
    {
        constexpr int NW2 = (144 * D_ + 255) / 256;        // 12
        const float* Wt = W2 + (size_t)t * (144 * D_);
        float wst[NW2];
#pragma unroll
        for (int i = 0; i < NW2; ++i) {
            int j = tid + i * 256;
            wst[i] = (j < 144 * D_) ? Wt[j] : 0.0f;        // all loads in flight
        }
        const float* W3t = W3 + (size_t)(4 * t) * (G_ * D_);
        float w3st[5];
#pragma unroll
        for (int i = 0; i < 5; ++i) w3st[i] = W3t[tid + i * 256];
#pragma unroll
        for (int i = 0; i < NW2; ++i) {
            int j = tid + i * 256;
            if (j < 144 * D_) {
                int k_orig = j / D_, o = j - k_orig * D_;
                int k_lds;
                if (k_orig < 4 * D_) {
                    int c = k_orig / D_;
                    k_lds = c * 32 + (k_orig - c * D_);
                } else {
                    k_lds = 4 * 32 + (k_orig - 4 * D_);
                }
                WT2[o * STRB2 + k_lds] = __float2half(wst[i]);
            }
        }
#pragma unroll
        for (int i = 0; i < 5; ++i) {          // G_*D_ = 1280 = 5*256
            int j = tid + i * 256;
            int k = j / D_, o = j - k * D_;
            WT3[0][o * STRB3 + k] = __float2half(w3st[i]);
        }
    }
    __syncthreads();

    const int quad = lane >> 4, l15 = lane & 15;
    const int nt = w >> 1, mhalf = w & 1;
    const int ocol = nt * 16 + l15;            // 0..31, valid < 20
    const int brow_base = mhalf * 128;
    const int shq = quad * 8;
    const int oc = ocol < D_ ? ocol : D_ - 1;

    // ---- 4 children (stratum 3): GEMM + BN + tanh -> h3loc ----
#pragma unroll
    for (int c = 0; c < 4; ++c) {
        // reg-stage next child's W3 (loads issue now, LDS writes after MFMA)
        float wreg[5];
        if (c < 3) {
            const float* W3n = W3 + (size_t)(4 * t + c + 1) * (G_ * D_);
#pragma unroll
            for (int i = 0; i < 5; ++i) wreg[i] = W3n[tid + i * 256];
        }
        const __half* WTc = WT3[c & 1];
        half8_t Bf0 = as_h8(*(const uint4*)(WTc + ocol * STRB3 + quad * 8));
        half8_t Bf1 = as_h8(*(const uint4*)(WTc + ocol * STRB3 + 32 + quad * 8));

        f32x4 acc[8];
#pragma unroll
        for (int mt = 0; mt < 8; ++mt) acc[mt] = (f32x4){0.f, 0.f, 0.f, 0.f};
#pragma unroll
        for (int mt = 0; mt < 8; ++mt) {
            const int bA = brow_base + mt * 16 + l15;
            const u64 gm = gmask[c][bA];
            acc[mt] = __builtin_amdgcn_mfma_f32_16x16x32_f16(
                bits8_to_h8(((uint)gm >> shq) & 0xFFu), Bf0, acc[mt], 0, 0, 0);
            acc[mt] = __builtin_amdgcn_mfma_f32_16x16x32_f16(
                bits8_to_h8(((uint)(gm >> 32) >> shq) & 0xFFu), Bf1, acc[mt], 0, 0, 0);
        }

        // drain reg-staged W3 into the other LDS buffer (covered by the sync)
        if (c < 3) {
#pragma unroll
            for (int i = 0; i < 5; ++i) {
                int j = tid + i * 256;
                int k = j / D_, o = j - k * D_;
                WT3[(c + 1) & 1][o * STRB3 + k] = __float2half(wreg[i]);
            }
        }

        float s = 0.f, q = 0.f;
#pragma unroll
        for (int mt = 0; mt < 8; ++mt)
#pragma unroll
            for (int r = 0; r < 4; ++r) {
                float z = acc[mt][r];
                s += z; q += z * z;
            }
        s += __shfl_xor(s, 16, 64); q += __shfl_xor(q, 16, 64);
        s += __shfl_xor(s, 32, 64); q += __shfl_xor(q, 32, 64);
        if (lane < 16) { sredb[c & 1][w][lane] = s; qredb[c & 1][w][lane] = q; }
        __syncthreads();
        const float S = sredb[c & 1][2 * nt][l15] + sredb[c & 1][2 * nt + 1][l15];
        const float Q = qredb[c & 1][2 * nt][l15] + qredb[c & 1][2 * nt + 1][l15];
        const float mu  = S * (1.0f / B_);
        const float var = fmaxf(Q * (1.0f / B_) - mu * mu, 0.0f);
        const float rstd = rsqrtf(var + EPS_);
        const float A = rstd * gv3[c * D_ + oc];
        const float C = bev3[c * D_ + oc] - mu * A;
        if (ocol < D_) {
#pragma unroll
            for (int mt = 0; mt < 8; ++mt)
#pragma unroll
                for (int r = 0; r < 4; ++r) {
                    float h = fast_tanh(fmaf(A, acc[mt][r], C));
                    int b = brow_base + mt * 16 + quad * 4 + r;
                    h3loc[(size_t)(c * B_ + b) * D_ + ocol] = __float2half(h);
                }
        }
    }
    __syncthreads();   // h3loc complete, visible to all waves

    // ---- stratum 2 GEMM: A from h3loc (LDS) + gene bits; B = WT2 ----
    half8_t Bf[6];
#pragma unroll
    for (int ks = 0; ks < 6; ++ks)
        Bf[ks] = as_h8(*(const uint4*)(WT2 + ocol * STRB2 + ks * 32 + quad * 8));

    f32x4 acc[8];
#pragma unroll
    for (int mt = 0; mt < 8; ++mt) acc[mt] = (f32x4){0.f, 0.f, 0.f, 0.f};
#pragma unroll
    for (int mt = 0; mt < 8; ++mt) {
        const int bA = brow_base + mt * 16 + l15;
        const u64 gm = gmask[4][bA];
#pragma unroll
        for (int c = 0; c < 4; ++c) {
            // h3 row is 20 halfs; quad*8 may run past 20 into the next row:
            // finite tanh values x zero-padded WT2 => exact 0 contribution.
            const __half* ap = h3loc + (size_t)(c * B_ + bA) * D_ + quad * 8;
            uint2 u0 = *(const uint2*)(ap);
            uint2 u1 = *(const uint2*)(ap + 4);
            acc[mt] = __builtin_amdgcn_mfma_f32_16x16x32_f16(
                as_h8(make_uint4(u0.x, u0.y, u1.x, u1.y)), Bf[c], acc[mt], 0, 0, 0);
        }
        acc[mt] = __builtin_amdgcn_mfma_f32_16x16x32_f16(
            bits8_to_h8(((uint)gm >> shq) & 0xFFu), Bf[4], acc[mt], 0, 0, 0);
        acc[mt] = __builtin_amdgcn_mfma_f32_16x16x32_f16(
            bits8_to_h8(((uint)(gm >> 32) >> shq) & 0xFFu), Bf[5], acc[mt], 0, 0, 0);
    }

    float s = 0.f, q = 0.f;
#pragma unroll
    for (int mt = 0; mt < 8; ++mt)
#pragma unroll
        for (int r = 0; r < 4; ++r) {
            float z = acc[mt][r];
            s += z; q += z * z;
        }
    s += __shfl_xor(s, 16, 64); q += __shfl_xor(q, 16, 64);
    s += __shfl_xor(s, 32, 64); q += __shfl_xor(q, 32, 64);
    if (lane < 16) { sredb[0][w][lane] = s; qredb[0][w][lane] = q; }
    __syncthreads();
    const float S = sredb[0][2 * nt][l15] + sredb[0][2 * nt + 1][l15];
    const float Q = qredb[0][2 * nt][l15] + qredb[0][2 * nt + 1][l15];
    const float mu  = S * (1.0f / B_);
    const float var = fmaxf(Q * (1.0f / B_) - mu * mu, 0.0f);
    const float rstd = rsqrtf(var + EPS_);
    const float A = rstd * gv2[oc];
    const float C = bev2[oc] - mu * A;

    // epilogue: LDS transpose (reuse WT2; Bf already in regs) + uint4 stores
    __half* ebuf = WT2;
    if (ocol < D_) {
#pragma unroll
        for (int mt = 0; mt < 8; ++mt)
#pragma unroll
            for (int r = 0; r < 4; ++r) {
                float h = fast_tanh(fmaf(A, acc[mt][r], C));
                int b = brow_base + mt * 16 + quad * 4 + r;
                ebuf[b * D_ + ocol] = __float2half(h);
            }
    }
    __syncthreads();
    const uint4* src4 = (const uint4*)ebuf;
    uint4* dst4 = (uint4*)(h2out + (size_t)t * (B_ * D_));
    for (int j = tid; j < (B_ * D_) / 8; j += 256) dst4[j] = src4[j];
}

// ---- MFMA GEMM + BN + tanh (stratum 1); fp16 term-major output --------------
template <int T, int NCHILD>
__global__ __launch_bounds__(256, 4) void k_gemm(const __half* __restrict__ hsrc,
                                                 const u64* __restrict__ gTb,
                                                 const float* __restrict__ W,
                                                 const float* __restrict__ g,
                                                 const float* __restrict__ be,
                                                 __half* __restrict__ hout) {
    constexpr int K_IN = NCHILD * 20 + 64;
    constexpr int NK = NCHILD + 2;
    constexpr int STRB = NCHILD ? 200 : 72;          // WT row stride in halfs
    constexpr int LDSH = (32 * STRB > B_ * D_) ? 32 * STRB : B_ * D_;
    __shared__ __align__(16) __half WT[LDSH];        // weights, then h-tile
    __shared__ float gv[D_], bev[D_];
    __shared__ float sred[4][16], qred[4][16];
    __shared__ u64 gmask[B_];                        // per-term gene bitmasks

    const int t = blockIdx.x, tid = threadIdx.x;
    const int w = tid >> 6, lane = tid & 63;

    // mask load (coalesced 2KB, in flight across the zero phase)
    const u64 mreg = gTb[(size_t)t * B_ + tid];

    if (NCHILD) {   // k-pad rows must be 0
        uint* WTu = (uint*)WT;
        for (int j = tid; j < 32 * STRB / 2; j += 256) WTu[j] = 0;
    }
    gmask[tid] = mreg;
    __syncthreads();

    if (tid < D_) { gv[tid] = g[t * D_ + tid]; bev[tid] = be[t * D_ + tid]; }
    {
        constexpr int NST = (K_IN * D_ + 255) / 256;
        const float* Wt = W + (size_t)t * (K_IN * D_);
        float wst[NST];
#pragma unroll
        for (int i = 0; i < NST; ++i) {
            int j = tid + i * 256;
            wst[i] = (j < K_IN * D_) ? Wt[j] : 0.0f;   // all loads in flight
        }
#pragma unroll
        for (int i = 0; i < NST; ++i) {
            int j = tid + i * 256;
            if (j < K_IN * D_) {
                int k_orig = j / D_, o = j - k_orig * D_;
                int k_lds;
                if (NCHILD && k_orig < NCHILD * D_) {
                    int c = k_orig / D_;
                    k_lds = c * 32 + (k_orig - c * D_);
                } else {
                    k_lds = NCHILD * 32 + (k_orig - NCHILD * D_);
                }
                WT[o * STRB + k_lds] = __float2half(wst[i]);
            }
        }
    }
    __syncthreads();

    const int quad = lane >> 4, l15 = lane & 15;
    const int nt = w >> 1, mhalf = w & 1;
    const int ocol = nt * 16 + l15;                   // 0..31, valid < 20
    const int brow_base = mhalf * 128;                // 8 m-tiles of 16 rows
    const int shq = quad * 8;

    half8_t Bf[NK];
#pragma unroll
    for (int ks = 0; ks < NK; ++ks)
        Bf[ks] = as_h8(*(const uint4*)(WT + ocol * STRB + ks * 32 + quad * 8));

    f32x4 acc[8];
#pragma unroll
    for (int mt = 0; mt < 8; ++mt) acc[mt] = (f32x4){0.f, 0.f, 0.f, 0.f};

#pragma unroll
    for (int mt = 0; mt < 8; ++mt) {
        const int bA = brow_base + mt * 16 + l15;     // A-operand row = lane&15
        const u64 gm = gmask[bA];                     // 64 gene bits (LDS)
#pragma unroll
        for (int c = 0; c < NCHILD; ++c) {
            // h row is 20 halfs; quad*8 may run past 20 into the next row:
            // finite garbage x zero-padded WT => exact 0 contribution.
            const __half* ap = hsrc + ((size_t)(NCHILD * t + c) * B_ + bA) * D_ + quad * 8;
            uint2 u0 = *(const uint2*)(ap);
            uint2 u1 = *(const uint2*)(ap + 4);
            acc[mt] = __builtin_amdgcn_mfma_f32_16x16x32_f16(
                as_h8(make_uint4(u0.x, u0.y, u1.x, u1.y)), Bf[c], acc[mt], 0, 0, 0);
        }
        acc[mt] = __builtin_amdgcn_mfma_f32_16x16x32_f16(
            bits8_to_h8(((uint)gm >> shq) & 0xFFu), Bf[NCHILD], acc[mt], 0, 0, 0);
        acc[mt] = __builtin_amdgcn_mfma_f32_16x16x32_f16(
            bits8_to_h8(((uint)(gm >> 32) >> shq) & 0xFFu), Bf[NCHILD + 1], acc[mt], 0, 0, 0);
    }

    // BN stats over batch: C/D layout row = quad*4+r, col = l15.
    float s = 0.f, q = 0.f;
#pragma unroll
    for (int mt = 0; mt < 8; ++mt)
#pragma unroll
        for (int r = 0; r < 4; ++r) {
            float z = acc[mt][r];
            s += z; q += z * z;
        }
    s += __shfl_xor(s, 16, 64); q += __shfl_xor(q, 16, 64);
    s += __shfl_xor(s, 32, 64); q += __shfl_xor(q, 32, 64);
    if (lane < 16) { sred[w][lane] = s; qred[w][lane] = q; }
    __syncthreads();        // after this no wave reads WT again (Bf in regs)
    const float S = sred[2 * nt][l15] + sred[2 * nt + 1][l15];
    const float Q = qred[2 * nt][l15] + qred[2 * nt + 1][l15];
    const float mu  = S * (1.0f / B_);
    const float var = fmaxf(Q * (1.0f / B_) - mu * mu, 0.0f);
    const float rstd = rsqrtf(var + EPS_);
    const int oc = ocol < D_ ? ocol : D_ - 1;
    const float A = rstd * gv[oc];
    const float C = bev[oc] - mu * A;

    // epilogue: LDS transpose (reuse WT) then dense uint4 stores (10 KB/term)
    if (ocol < D_) {
#pragma unroll
        for (int mt = 0; mt < 8; ++mt)
#pragma unroll
            for (int r = 0; r < 4; ++r) {
                float h = fast_tanh(fmaf(A, acc[mt][r], C));
                int b = brow_base + mt * 16 + quad * 4 + r;
                WT[b * D_ + ocol] = __float2half(h);
            }
    }
    __syncthreads();
    const uint4* src4 = (const uint4*)WT;
    uint4* dst4 = (uint4*)(hout + (size_t)t * (B_ * D_));
    for (int j = tid; j < (B_ * D_) / 8; j += 256) dst4[j] = src4[j];
}

// ---- root GEMV, K-split x4 (h1 fp16 term-major [t][b][20]) ------------------
__global__ __launch_bounds__(256, 4) void k_stage0a(const __half* __restrict__ h1,
                                                    const float* __restrict__ genes0,
                                                    const float* __restrict__ W0,
                                                    float* __restrict__ z0p) {
    const int b = blockIdx.x >> 2, s = blockIdx.x & 3, tid = threadIdx.x;
    const int kbase = 640 * s;
    float acc[D_] = {};
#pragma unroll
    for (int j = 0; j < 3; ++j) {
        int kl = tid + 256 * j;
        if (kl < 640) {
            int k = kbase + kl;
            int tt = k / D_, o = k - tt * D_;
            float xk = __half2float(h1[((size_t)tt * B_ + b) * D_ + o]);
            const float4* w = (const float4*)(W0 + (size_t)k * D_);
#pragma unroll
            for (int v = 0; v < D_ / 4; ++v) {
                float4 f = w[v];
                acc[4 * v + 0] = fmaf(xk, f.x, acc[4 * v + 0]);
                acc[4 * v + 1] = fmaf(xk, f.y, acc[4 * v + 1]);
                acc[4 * v + 2] = fmaf(xk, f.z, acc[4 * v + 2]);
                acc[4 * v + 3] = fmaf(xk, f.w, acc[4 * v + 3]);
            }
        }
    }
    if (s == 3 && tid < G_) {
        float xk = genes0[(size_t)b * G_ + tid];
        const float4* w = (const float4*)(W0 + (size_t)(T1_ * D_ + tid) * D_);
#pragma unroll
        for (int v = 0; v < D_ / 4; ++v) {
            float4 f = w[v];
            acc[4 * v + 0] = fmaf(xk, f.x, acc[4 * v + 0]);
            acc[4 * v + 1] = fmaf(xk, f.y, acc[4 * v + 1]);
            acc[4 * v + 2] = fmaf(xk, f.z, acc[4 * v + 2]);
            acc[4 * v + 3] = fmaf(xk, f.w, acc[4 * v + 3]);
        }
    }
    __shared__ float sred[4][D_];
    const int lane = tid & 63, wave = tid >> 6;
#pragma unroll
    for (int off = 32; off; off >>= 1)
#pragma unroll
        for (int o = 0; o < D_; ++o) acc[o] += __shfl_xor(acc[o], off, 64);
    if (lane == 0)
#pragma unroll
        for (int o = 0; o < D_; ++o) sred[wave][o] = acc[o];
    __syncthreads();
    if (tid < D_)
        z0p[((size_t)b * 4 + s) * D_ + tid] =
            sred[0][tid] + sred[1][tid] + sred[2][tid] + sred[3][tid];
}

// ---- root BN + tanh + head --------------------------------------------------
__global__ __launch_bounds__(256) void k_stage0b(const float* __restrict__ z0p,
                                                 const float* __restrict__ g0,
                                                 const float* __restrict__ be0,
                                                 const float* __restrict__ hw0,
                                                 const float* __restrict__ hb0,
                                                 float* __restrict__ out) {
    const int tid = threadIdx.x;   // == batch row
    float acc[D_] = {};
#pragma unroll
    for (int s = 0; s < 4; ++s) {
        const float4* zp = (const float4*)(z0p + ((size_t)tid * 4 + s) * D_);
#pragma unroll
        for (int v = 0; v < D_ / 4; ++v) {
            float4 f = zp[v];
            acc[4 * v + 0] += f.x; acc[4 * v + 1] += f.y;
            acc[4 * v + 2] += f.z; acc[4 * v + 3] += f.w;
        }
    }
    __shared__ float sred[4][D_], qred[4][D_], Avec[D_], Cvec[D_], hwv[D_ + 1];
    const int lane = tid & 63, wave = tid >> 6;
    float s[D_], q[D_];
#pragma unroll
    for (int o = 0; o < D_; ++o) { s[o] = acc[o]; q[o] = acc[o] * acc[o]; }
#pragma unroll
    for (int off = 32; off; off >>= 1) {
#pragma unroll
        for (int o = 0; o < D_; ++o) {
            s[o] += __shfl_xor(s[o], off, 64);
            q[o] += __shfl_xor(q[o], off, 64);
        }
    }
    if (lane == 0) {
#pragma unroll
        for (int o = 0; o < D_; ++o) { sred[wave][o] = s[o]; qred[wave][o] = q[o]; }
    }
    __syncthreads();
    if (tid < D_) {
        float S = sred[0][tid] + sred[1][tid] + sred[2][tid] + sred[3][tid];
        float Q = qred[0][tid] + qred[1][tid] + qred[2][tid] + qred[3][tid];
        float mu  = S * (1.0f / B_);
        float var = fmaxf(Q * (1.0f / B_) - mu * mu, 0.0f);
        float rstd = rsqrtf(var + EPS_);
        float A = rstd * g0[tid];
        Avec[tid] = A;
        Cvec[tid] = be0[tid] - mu * A;
        hwv[tid] = hw0[tid];
    }
    if (tid == 0) hwv[D_] = hb0[0];
    __syncthreads();
    float pred = hwv[D_];
#pragma unroll
    for (int o = 0; o < D_; ++o) {
        float h = fast_tanh(fmaf(acc[o], Avec[o], Cvec[o]));
        pred = fmaf(h, hwv[o], pred);
    }
    out[tid] = pred;
}

extern "C" void kernel_launch(void* const* d_in, const int* in_sizes, int n_in,
                              void* d_out, int out_size, void* d_ws, size_t ws_size,
                              hipStream_t stream) {
    const float* genes3 = (const float*)d_in[0];
    const float* genes2 = (const float*)d_in[1];
    const float* genes1 = (const float*)d_in[2];
    const float* genes0 = (const float*)d_in[3];
    const float* W3  = (const float*)d_in[4];
    const float* g3  = (const float*)d_in[6];
    const float* be3 = (const float*)d_in[7];
    const float* W2  = (const float*)d_in[8];
    const float* g2  = (const float*)d_in[10];
    const float* be2 = (const float*)d_in[11];
    const float* W1  = (const float*)d_in[12];
    const float* g1  = (const float*)d_in[14];
    const float* be1 = (const float*)d_in[15];
    const float* W0  = (const float*)d_in[16];
    const float* g0  = (const float*)d_in[18];
    const float* be0 = (const float*)d_in[19];
    const float* hw0 = (const float*)d_in[20];
    const float* hb0 = (const float*)d_in[21];

    char* wsb = (char*)d_ws;
    u64* gTb3 = (u64*)(wsb + OFF_GTB3);
    u64* gTb2 = (u64*)(wsb + OFF_GTB2);
    u64* gTb1 = (u64*)(wsb + OFF_GTB1);
    __half* h2  = (__half*)(wsb + OFF_H2B);
    __half* h1  = (__half*)(wsb + OFF_H1B);
    float*  z0p = (float*)(wsb + OFF_Z0B);

    void* kargs[] = {
        (void*)&genes3, (void*)&genes2, (void*)&genes1,
        (void*)&gTb3, (void*)&gTb2, (void*)&gTb1,
        (void*)&W3, (void*)&g3, (void*)&be3,
        (void*)&W2, (void*)&g2, (void*)&be2,
        (void*)&h2};
    hipLaunchCooperativeKernel((void*)k_packgemm32, dim3(T2_), dim3(256),
                               kargs, 0, stream);
    k_gemm<T1_, 4><<<T1_, 256, 0, stream>>>(h2, gTb1, W1, g1, be1, h1);
    k_stage0a<<<B_ * 4, 256, 0, stream>>>(h1, genes0, W0, z0p);
    k_stage0b<<<1, 256, 0, stream>>>(z0p, g0, be0, hw0, hb0, (float*)d_out);
}

// Round 9
// 305.078 us; speedup vs baseline: 1.3752x; 1.3752x over previous
//
#include <hip/hip_runtime.h>
#include <hip/hip_fp16.h>

// DCell forward, MI355X (gfx950). All inputs/outputs fp32.
// R21: R19 base (standalone sequential pack; cooperative R20 regressed 114us
// because grid.sync forced the pack to the gemm's 2-block/CU occupancy).
// NEW: k_gemm32 stratum-3 children computed WAVE-PARALLEL (wave w owns child
// w entirely: 16 mt x 2 nt x K64 = 64 MFMA, acc[16][2] in VGPRs). BN is
// wave-local (register sums + 2 shfl_xor, no barrier); child masks live in
// 16 u64 regs/lane (coalesced 128B loads). s3 phase: 8 barriers -> 1.
// LDS: WT3 x4 children (+9KB), gmask shrunk to s2-only (-8KB) = 73.8KB,
// still 2 blocks/CU. Same MFMA ops; BN fp32 sum order differs (within tol).
// Kept: batched W staging, fused s3+s2 (no h3 round-trip), block BN for s2.
// ws: [gTb3 | gTb2 | gTb1 | h2 fp16 | h1 fp16 | z0p] ~18 MB.

#define DEV static __device__ __forceinline__

constexpr int B_  = 256, G_ = 64, D_ = 20;
constexpr int T3_ = 2048, T2_ = 512, T1_ = 128;
constexpr float EPS_ = 1e-5f;

typedef unsigned char u8;
typedef unsigned long long u64;

constexpr size_t OFF_GTB3 = 0;
constexpr size_t SZ_GTB3 = (size_t)T3_ * B_ * 8;
constexpr size_t OFF_GTB2 = OFF_GTB3 + SZ_GTB3;
constexpr size_t SZ_GTB2 = (size_t)T2_ * B_ * 8;
constexpr size_t OFF_GTB1 = OFF_GTB2 + SZ_GTB2;
constexpr size_t SZ_GTB1 = (size_t)T1_ * B_ * 8;
constexpr size_t OFF_H2B = OFF_GTB1 + SZ_GTB1;
constexpr size_t SZ_H2 = (size_t)T2_ * B_ * D_ * 2;
constexpr size_t OFF_H1B = OFF_H2B + SZ_H2;
constexpr size_t SZ_H1 = (size_t)T1_ * B_ * D_ * 2;
constexpr size_t OFF_Z0B = OFF_H1B + SZ_H1;

typedef _Float16 half8_t __attribute__((ext_vector_type(8)));
typedef float f32x4 __attribute__((ext_vector_type(4)));

DEV half8_t as_h8(uint4 u) {
    union { uint4 u4; half8_t h; } c; c.u4 = u; return c.h;
}

// 8 gene BITS -> half8 {0.0h,1.0h}. Exact (no carries: operands are 0/1).
DEV half8_t bits8_to_h8(uint byte) {
    uint4 r;
    r.x = ((byte & 1u)        | ((byte & 2u)   << 15)) * 0x3C00u;
    r.y = (((byte >> 2) & 1u) | ((byte & 8u)   << 13)) * 0x3C00u;
    r.z = (((byte >> 4) & 1u) | ((byte & 32u)  << 11)) * 0x3C00u;
    r.w = (((byte >> 6) & 1u) | ((byte & 128u) << 9))  * 0x3C00u;
    return as_h8(r);
}

DEV float fast_tanh(float x) {
    float e = __expf(2.0f * x);
    return fmaf(-2.0f, __builtin_amdgcn_rcpf(e + 1.0f), 1.0f);
}

// ---- ballot bit-pack: genes fp32 [256][T][64] -> gTb u64 [t][b] -------------
// SEQUENTIAL streaming: consecutive R rows -> contiguous addresses.
__global__ __launch_bounds__(256, 8) void k_pack_all(
        const float* __restrict__ g3s, const float* __restrict__ g2s,
        const float* __restrict__ g1s,
        u64* __restrict__ d3, u64* __restrict__ d2, u64* __restrict__ d1) {
    constexpr int R3 = B_ * T3_;          // 524288
    constexpr int R2 = B_ * T2_;          // 131072
    const int lane = threadIdx.x & 63;
    int R0 = (blockIdx.x * 4 + (threadIdx.x >> 6)) * 8;
    const float* src; u64* dst; int shift;
    if (R0 < R3)            { src = g3s; dst = d3; shift = 11; }
    else if (R0 < R3 + R2)  { R0 -= R3; src = g2s; dst = d2; shift = 9; }
    else                    { R0 -= R3 + R2; src = g1s; dst = d1; shift = 7; }

    const float* p = src + (size_t)R0 * G_ + lane;
    float x[8];
#pragma unroll
    for (int r = 0; r < 8; ++r) x[r] = p[r * G_];
    u64 m[8];
#pragma unroll
    for (int r = 0; r < 8; ++r) m[r] = __ballot(x[r] != 0.0f);

    if (lane < 8) {
        u64 v = m[0];
        v = lane == 1 ? m[1] : v;
        v = lane == 2 ? m[2] : v;
        v = lane == 3 ? m[3] : v;
        v = lane == 4 ? m[4] : v;
        v = lane == 5 ? m[5] : v;
        v = lane == 6 ? m[6] : v;
        v = lane == 7 ? m[7] : v;
        const int R = R0 + lane;
        const int b = R >> shift, t = R - (b << shift);
        dst[(size_t)t * B_ + b] = v;
    }
}

// ---- fused strata 3+2: one block per s2 term; s3 children wave-parallel ----
__global__ __launch_bounds__(256, 2) void k_gemm32(
        const u64* __restrict__ gTb3, const u64* __restrict__ gTb2,
        const float* __restrict__ W3, const float* __restrict__ g3,
        const float* __restrict__ be3,
        const float* __restrict__ W2, const float* __restrict__ g2,
        const float* __restrict__ be2, __half* __restrict__ h2out) {
    constexpr int STRB3 = 72, STRB2 = 200;
    __shared__ __align__(16) __half h3loc[4 * B_ * D_ + 16];  // +pad for A-overrun
    __shared__ __align__(16) __half WT3[4][32 * STRB3];
    __shared__ __align__(16) __half WT2[32 * STRB2];
    __shared__ u64 gmask2[B_];
    __shared__ float sred2[4][16], qred2[4][16];
    __shared__ float gv3[4 * D_], bev3[4 * D_], gv2[D_], bev2[D_];

    const int t = blockIdx.x, tid = threadIdx.x;
    const int w = tid >> 6, lane = tid & 63;
    const int quad = lane >> 4, l15 = lane & 15;
    const int shq = quad * 8;

    // ---- s3 masks for this wave's child: 16 coalesced 128B loads, in flight
    u64 gm[16];
#pragma unroll
    for (int mt = 0; mt < 16; ++mt)
        gm[mt] = gTb3[(size_t)(4 * t + w) * B_ + mt * 16 + l15];
    const u64 m2 = gTb2[(size_t)t * B_ + tid];

    // zero WT2 k-pad + h3loc tail pad while mask loads in flight
    {
        uint* WTu = (uint*)WT2;
        for (int j = tid; j < 32 * STRB2 / 2; j += 256) WTu[j] = 0;
        if (tid < 16) h3loc[4 * B_ * D_ + tid] = __half(0.0f);
    }
    gmask2[tid] = m2;

    // BN params
    if (tid < 4 * D_) {
        gv3[tid] = g3[(size_t)(4 * t) * D_ + tid];
        bev3[tid] = be3[(size_t)(4 * t) * D_ + tid];
    } else if (tid < 5 * D_) {
        gv2[tid - 4 * D_] = g2[(size_t)t * D_ + (tid - 4 * D_)];
        bev2[tid - 4 * D_] = be2[(size_t)t * D_ + (tid - 4 * D_)];
    }

    // batched staging: W3 all 4 children (20 loads/thr) + W2 (12 loads/thr)
    {
        const float* W3t = W3 + (size_t)(4 * t) * (G_ * D_);
        float w3st[20];
#pragma unroll
        for (int i = 0; i < 20; ++i) w3st[i] = W3t[tid + i * 256];
        constexpr int NW2 = (144 * D_ + 255) / 256;        // 12
        const float* Wt = W2 + (size_t)t * (144 * D_);
        float wst[NW2];
#pragma unroll
        for (int i = 0; i < NW2; ++i) {
            int j = tid + i * 256;
            wst[i] = (j < 144 * D_) ? Wt[j] : 0.0f;
        }
#pragma unroll
        for (int i = 0; i < 20; ++i) {
            int j = tid + i * 256;                 // 0..5119
            int c = j / (G_ * D_);
            int jj = j - c * (G_ * D_);
            int k = jj / D_, o = jj - k * D_;
            WT3[c][o * STRB3 + k] = __float2half(w3st[i]);
        }
#pragma unroll
        for (int i = 0; i < NW2; ++i) {
            int j = tid + i * 256;
            if (j < 144 * D_) {
                int k_orig = j / D_, o = j - k_orig * D_;
                int k_lds;
                if (k_orig < 4 * D_) {
                    int c = k_orig / D_;
                    k_lds = c * 32 + (k_orig - c * D_);
                } else {
                    k_lds = 4 * 32 + (k_orig - 4 * D_);
                }
                WT2[o * STRB2 + k_lds] = __float2half(wst[i]);
            }
        }
    }
    __syncthreads();

    // ---- stratum 3: wave w computes child w fully, no barriers ----
    {
        const __half* WTc = WT3[w];
        half8_t Bf3[2][2];
#pragma unroll
        for (int nt = 0; nt < 2; ++nt)
#pragma unroll
            for (int ks = 0; ks < 2; ++ks)
                Bf3[nt][ks] = as_h8(*(const uint4*)(
                    WTc + (nt * 16 + l15) * STRB3 + ks * 32 + quad * 8));

        f32x4 acc3[16][2];
#pragma unroll
        for (int mt = 0; mt < 16; ++mt)
#pragma unroll
            for (int nt = 0; nt < 2; ++nt)
                acc3[mt][nt] = (f32x4){0.f, 0.f, 0.f, 0.f};

#pragma unroll
        for (int mt = 0; mt < 16; ++mt) {
            half8_t a0 = bits8_to_h8(((uint)gm[mt] >> shq) & 0xFFu);
            half8_t a1 = bits8_to_h8(((uint)(gm[mt] >> 32) >> shq) & 0xFFu);
#pragma unroll
            for (int nt = 0; nt < 2; ++nt) {
                acc3[mt][nt] = __builtin_amdgcn_mfma_f32_16x16x32_f16(
                    a0, Bf3[nt][0], acc3[mt][nt], 0, 0, 0);
                acc3[mt][nt] = __builtin_amdgcn_mfma_f32_16x16x32_f16(
                    a1, Bf3[nt][1], acc3[mt][nt], 0, 0, 0);
            }
        }

        // wave-local BN + tanh -> h3loc (no cross-wave traffic)
#pragma unroll
        for (int nt = 0; nt < 2; ++nt) {
            float s = 0.f, q = 0.f;
#pragma unroll
            for (int mt = 0; mt < 16; ++mt)
#pragma unroll
                for (int r = 0; r < 4; ++r) {
                    float z = acc3[mt][nt][r];
                    s += z; q += z * z;
                }
            s += __shfl_xor(s, 16, 64); q += __shfl_xor(q, 16, 64);
            s += __shfl_xor(s, 32, 64); q += __shfl_xor(q, 32, 64);
            const int col = nt * 16 + l15;
            const int oc = col < D_ ? col : D_ - 1;
            const float mu  = s * (1.0f / B_);
            const float var = fmaxf(q * (1.0f / B_) - mu * mu, 0.0f);
            const float rstd = rsqrtf(var + EPS_);
            const float A = rstd * gv3[w * D_ + oc];
            const float C = bev3[w * D_ + oc] - mu * A;
            if (col < D_) {
#pragma unroll
                for (int mt = 0; mt < 16; ++mt)
#pragma unroll
                    for (int r = 0; r < 4; ++r) {
                        float h = fast_tanh(fmaf(A, acc3[mt][nt][r], C));
                        int row = mt * 16 + quad * 4 + r;
                        h3loc[(size_t)(w * B_ + row) * D_ + col] = __float2half(h);
                    }
            }
        }
    }
    __syncthreads();   // h3loc complete, visible to all waves

    // ---- stratum 2 GEMM: A from h3loc (LDS) + gene bits; B = WT2 ----
    const int nt = w >> 1, mhalf = w & 1;
    const int ocol = nt * 16 + l15;            // 0..31, valid < 20
    const int brow_base = mhalf * 128;
    const int oc = ocol < D_ ? ocol : D_ - 1;

    half8_t Bf[6];
#pragma unroll
    for (int ks = 0; ks < 6; ++ks)
        Bf[ks] = as_h8(*(const uint4*)(WT2 + ocol * STRB2 + ks * 32 + quad * 8));

    f32x4 acc[8];
#pragma unroll
    for (int mt = 0; mt < 8; ++mt) acc[mt] = (f32x4){0.f, 0.f, 0.f, 0.f};
#pragma unroll
    for (int mt = 0; mt < 8; ++mt) {
        const int bA = brow_base + mt * 16 + l15;
        const u64 g2m = gmask2[bA];
#pragma unroll
        for (int c = 0; c < 4; ++c) {
            // h3 row is 20 halfs; quad*8 may run past 20 into the next row:
            // finite tanh values x zero-padded WT2 => exact 0 contribution.
            const __half* ap = h3loc + (size_t)(c * B_ + bA) * D_ + quad * 8;
            uint2 u0 = *(const uint2*)(ap);
            uint2 u1 = *(const uint2*)(ap + 4);
            acc[mt] = __builtin_amdgcn_mfma_f32_16x16x32_f16(
                as_h8(make_uint4(u0.x, u0.y, u1.x, u1.y)), Bf[c], acc[mt], 0, 0, 0);
        }
        acc[mt] = __builtin_amdgcn_mfma_f32_16x16x32_f16(
            bits8_to_h8(((uint)g2m >> shq) & 0xFFu), Bf[4], acc[mt], 0, 0, 0);
        acc[mt] = __builtin_amdgcn_mfma_f32_16x16x32_f16(
            bits8_to_h8(((uint)(g2m >> 32) >> shq) & 0xFFu), Bf[5], acc[mt], 0, 0, 0);
    }

    float s = 0.f, q = 0.f;
#pragma unroll
    for (int mt = 0; mt < 8; ++mt)
#pragma unroll
        for (int r = 0; r < 4; ++r) {
            float z = acc[mt][r];
            s += z; q += z * z;
        }
    s += __shfl_xor(s, 16, 64); q += __shfl_xor(q, 16, 64);
    s += __shfl_xor(s, 32, 64); q += __shfl_xor(q, 32, 64);
    if (lane < 16) { sred2[w][lane] = s; qred2[w][lane] = q; }
    __syncthreads();
    const float S = sred2[2 * nt][l15] + sred2[2 * nt + 1][l15];
    const float Q = qred2[2 * nt][l15] + qred2[2 * nt + 1][l15];
    const float mu  = S * (1.0f / B_);
    const float var = fmaxf(Q * (1.0f / B_) - mu * mu, 0.0f);
    const float rstd = rsqrtf(var + EPS_);
    const float A = rstd * gv2[oc];
    const float C = bev2[oc] - mu * A;

    // epilogue: LDS transpose (reuse WT2; Bf already in regs) + uint4 stores
    __half* ebuf = WT2;
    if (ocol < D_) {
#pragma unroll
        for (int mt = 0; mt < 8; ++mt)
#pragma unroll
            for (int r = 0; r < 4; ++r) {
                float h = fast_tanh(fmaf(A, acc[mt][r], C));
                int b = brow_base + mt * 16 + quad * 4 + r;
                ebuf[b * D_ + ocol] = __float2half(h);
            }
    }
    __syncthreads();
    const uint4* src4 = (const uint4*)ebuf;
    uint4* dst4 = (uint4*)(h2out + (size_t)t * (B_ * D_));
    for (int j = tid; j < (B_ * D_) / 8; j += 256) dst4[j] = src4[j];
}

// ---- MFMA GEMM + BN + tanh (stratum 1); fp16 term-major output --------------
template <int T, int NCHILD>
__global__ __launch_bounds__(256, 4) void k_gemm(const __half* __restrict__ hsrc,
                                                 const u64* __restrict__ gTb,
                                                 const float* __restrict__ W,
                                                 const float* __restrict__ g,
                                                 const float* __restrict__ be,
                                                 __half* __restrict__ hout) {
    constexpr int K_IN = NCHILD * 20 + 64;
    constexpr int NK = NCHILD + 2;
    constexpr int STRB = NCHILD ? 200 : 72;          // WT row stride in halfs
    constexpr int LDSH = (32 * STRB > B_ * D_) ? 32 * STRB : B_ * D_;
    __shared__ __align__(16) __half WT[LDSH];        // weights, then h-tile
    __shared__ float gv[D_], bev[D_];
    __shared__ float sred[4][16], qred[4][16];
    __shared__ u64 gmask[B_];                        // per-term gene bitmasks

    const int t = blockIdx.x, tid = threadIdx.x;
    const int w = tid >> 6, lane = tid & 63;

    // mask load (coalesced 2KB, in flight across the zero phase)
    const u64 mreg = gTb[(size_t)t * B_ + tid];

    if (NCHILD) {   // k-pad rows must be 0
        uint* WTu = (uint*)WT;
        for (int j = tid; j < 32 * STRB / 2; j += 256) WTu[j] = 0;
    }
    gmask[tid] = mreg;
    __syncthreads();

    if (tid < D_) { gv[tid] = g[t * D_ + tid]; bev[tid] = be[t * D_ + tid]; }
    {
        constexpr int NST = (K_IN * D_ + 255) / 256;
        const float* Wt = W + (size_t)t * (K_IN * D_);
        float wst[NST];
#pragma unroll
        for (int i = 0; i < NST; ++i) {
            int j = tid + i * 256;
            wst[i] = (j < K_IN * D_) ? Wt[j] : 0.0f;   // all loads in flight
        }
#pragma unroll
        for (int i = 0; i < NST; ++i) {
            int j = tid + i * 256;
            if (j < K_IN * D_) {
                int k_orig = j / D_, o = j - k_orig * D_;
                int k_lds;
                if (NCHILD && k_orig < NCHILD * D_) {
                    int c = k_orig / D_;
                    k_lds = c * 32 + (k_orig - c * D_);
                } else {
                    k_lds = NCHILD * 32 + (k_orig - NCHILD * D_);
                }
                WT[o * STRB + k_lds] = __float2half(wst[i]);
            }
        }
    }
    __syncthreads();

    const int quad = lane >> 4, l15 = lane & 15;
    const int nt = w >> 1, mhalf = w & 1;
    const int ocol = nt * 16 + l15;                   // 0..31, valid < 20
    const int brow_base = mhalf * 128;                // 8 m-tiles of 16 rows
    const int shq = quad * 8;

    half8_t Bf[NK];
#pragma unroll
    for (int ks = 0; ks < NK; ++ks)
        Bf[ks] = as_h8(*(const uint4*)(WT + ocol * STRB + ks * 32 + quad * 8));

    f32x4 acc[8];
#pragma unroll
    for (int mt = 0; mt < 8; ++mt) acc[mt] = (f32x4){0.f, 0.f, 0.f, 0.f};

#pragma unroll
    for (int mt = 0; mt < 8; ++mt) {
        const int bA = brow_base + mt * 16 + l15;     // A-operand row = lane&15
        const u64 gm = gmask[bA];                     // 64 gene bits (LDS)
#pragma unroll
        for (int c = 0; c < NCHILD; ++c) {
            // h row is 20 halfs; quad*8 may run past 20 into the next row:
            // finite garbage x zero-padded WT => exact 0 contribution.
            const __half* ap = hsrc + ((size_t)(NCHILD * t + c) * B_ + bA) * D_ + quad * 8;
            uint2 u0 = *(const uint2*)(ap);
            uint2 u1 = *(const uint2*)(ap + 4);
            acc[mt] = __builtin_amdgcn_mfma_f32_16x16x32_f16(
                as_h8(make_uint4(u0.x, u0.y, u1.x, u1.y)), Bf[c], acc[mt], 0, 0, 0);
        }
        acc[mt] = __builtin_amdgcn_mfma_f32_16x16x32_f16(
            bits8_to_h8(((uint)gm >> shq) & 0xFFu), Bf[NCHILD], acc[mt], 0, 0, 0);
        acc[mt] = __builtin_amdgcn_mfma_f32_16x16x32_f16(
            bits8_to_h8(((uint)(gm >> 32) >> shq) & 0xFFu), Bf[NCHILD + 1], acc[mt], 0, 0, 0);
    }

    // BN stats over batch: C/D layout row = quad*4+r, col = l15.
    float s = 0.f, q = 0.f;
#pragma unroll
    for (int mt = 0; mt < 8; ++mt)
#pragma unroll
        for (int r = 0; r < 4; ++r) {
            float z = acc[mt][r];
            s += z; q += z * z;
        }
    s += __shfl_xor(s, 16, 64); q += __shfl_xor(q, 16, 64);
    s += __shfl_xor(s, 32, 64); q += __shfl_xor(q, 32, 64);
    if (lane < 16) { sred[w][lane] = s; qred[w][lane] = q; }
    __syncthreads();        // after this no wave reads WT again (Bf in regs)
    const float S = sred[2 * nt][l15] + sred[2 * nt + 1][l15];
    const float Q = qred[2 * nt][l15] + qred[2 * nt + 1][l15];
    const float mu  = S * (1.0f / B_);
    const float var = fmaxf(Q * (1.0f / B_) - mu * mu, 0.0f);
    const float rstd = rsqrtf(var + EPS_);
    const int oc = ocol < D_ ? ocol : D_ - 1;
    const float A = rstd * gv[oc];
    const float C = bev[oc] - mu * A;

    // epilogue: LDS transpose (reuse WT) then dense uint4 stores (10 KB/term)
    if (ocol < D_) {
#pragma unroll
        for (int mt = 0; mt < 8; ++mt)
#pragma unroll
            for (int r = 0; r < 4; ++r) {
                float h = fast_tanh(fmaf(A, acc[mt][r], C));
                int b = brow_base + mt * 16 + quad * 4 + r;
                WT[b * D_ + ocol] = __float2half(h);
            }
    }
    __syncthreads();
    const uint4* src4 = (const uint4*)WT;
    uint4* dst4 = (uint4*)(hout + (size_t)t * (B_ * D_));
    for (int j = tid; j < (B_ * D_) / 8; j += 256) dst4[j] = src4[j];
}

// ---- root GEMV, K-split x4 (h1 fp16 term-major [t][b][20]) ------------------
__global__ __launch_bounds__(256, 4) void k_stage0a(const __half* __restrict__ h1,
                                                    const float* __restrict__ genes0,
                                                    const float* __restrict__ W0,
                                                    float* __restrict__ z0p) {
    const int b = blockIdx.x >> 2, s = blockIdx.x & 3, tid = threadIdx.x;
    const int kbase = 640 * s;
    float acc[D_] = {};
#pragma unroll
    for (int j = 0; j < 3; ++j) {
        int kl = tid + 256 * j;
        if (kl < 640) {
            int k = kbase + kl;
            int tt = k / D_, o = k - tt * D_;
            float xk = __half2float(h1[((size_t)tt * B_ + b) * D_ + o]);
            const float4* w = (const float4*)(W0 + (size_t)k * D_);
#pragma unroll
            for (int v = 0; v < D_ / 4; ++v) {
                float4 f = w[v];
                acc[4 * v + 0] = fmaf(xk, f.x, acc[4 * v + 0]);
                acc[4 * v + 1] = fmaf(xk, f.y, acc[4 * v + 1]);
                acc[4 * v + 2] = fmaf(xk, f.z, acc[4 * v + 2]);
                acc[4 * v + 3] = fmaf(xk, f.w, acc[4 * v + 3]);
            }
        }
    }
    if (s == 3 && tid < G_) {
        float xk = genes0[(size_t)b * G_ + tid];
        const float4* w = (const float4*)(W0 + (size_t)(T1_ * D_ + tid) * D_);
#pragma unroll
        for (int v = 0; v < D_ / 4; ++v) {
            float4 f = w[v];
            acc[4 * v + 0] = fmaf(xk, f.x, acc[4 * v + 0]);
            acc[4 * v + 1] = fmaf(xk, f.y, acc[4 * v + 1]);
            acc[4 * v + 2] = fmaf(xk, f.z, acc[4 * v + 2]);
            acc[4 * v + 3] = fmaf(xk, f.w, acc[4 * v + 3]);
        }
    }
    __shared__ float sred[4][D_];
    const int lane = tid & 63, wave = tid >> 6;
#pragma unroll
    for (int off = 32; off; off >>= 1)
#pragma unroll
        for (int o = 0; o < D_; ++o) acc[o] += __shfl_xor(acc[o], off, 64);
    if (lane == 0)
#pragma unroll
        for (int o = 0; o < D_; ++o) sred[wave][o] = acc[o];
    __syncthreads();
    if (tid < D_)
        z0p[((size_t)b * 4 + s) * D_ + tid] =
            sred[0][tid] + sred[1][tid] + sred[2][tid] + sred[3][tid];
}

// ---- root BN + tanh + head --------------------------------------------------
__global__ __launch_bounds__(256) void k_stage0b(const float* __restrict__ z0p,
                                                 const float* __restrict__ g0,
                                                 const float* __restrict__ be0,
                                                 const float* __restrict__ hw0,
                                                 const float* __restrict__ hb0,
                                                 float* __restrict__ out) {
    const int tid = threadIdx.x;   // == batch row
    float acc[D_] = {};
#pragma unroll
    for (int s = 0; s < 4; ++s) {
        const float4* zp = (const float4*)(z0p + ((size_t)tid * 4 + s) * D_);
#pragma unroll
        for (int v = 0; v < D_ / 4; ++v) {
            float4 f = zp[v];
            acc[4 * v + 0] += f.x; acc[4 * v + 1] += f.y;
            acc[4 * v + 2] += f.z; acc[4 * v + 3] += f.w;
        }
    }
    __shared__ float sred[4][D_], qred[4][D_], Avec[D_], Cvec[D_], hwv[D_ + 1];
    const int lane = tid & 63, wave = tid >> 6;
    float s[D_], q[D_];
#pragma unroll
    for (int o = 0; o < D_; ++o) { s[o] = acc[o]; q[o] = acc[o] * acc[o]; }
#pragma unroll
    for (int off = 32; off; off >>= 1) {
#pragma unroll
        for (int o = 0; o < D_; ++o) {
            s[o] += __shfl_xor(s[o], off, 64);
            q[o] += __shfl_xor(q[o], off, 64);
        }
    }
    if (lane == 0) {
#pragma unroll
        for (int o = 0; o < D_; ++o) { sred[wave][o] = s[o]; qred[wave][o] = q[o]; }
    }
    __syncthreads();
    if (tid < D_) {
        float S = sred[0][tid] + sred[1][tid] + sred[2][tid] + sred[3][tid];
        float Q = qred[0][tid] + qred[1][tid] + qred[2][tid] + qred[3][tid];
        float mu  = S * (1.0f / B_);
        float var = fmaxf(Q * (1.0f / B_) - mu * mu, 0.0f);
        float rstd = rsqrtf(var + EPS_);
        float A = rstd * g0[tid];
        Avec[tid] = A;
        Cvec[tid] = be0[tid] - mu * A;
        hwv[tid] = hw0[tid];
    }
    if (tid == 0) hwv[D_] = hb0[0];
    __syncthreads();
    float pred = hwv[D_];
#pragma unroll
    for (int o = 0; o < D_; ++o) {
        float h = fast_tanh(fmaf(acc[o], Avec[o], Cvec[o]));
        pred = fmaf(h, hwv[o], pred);
    }
    out[tid] = pred;
}

extern "C" void kernel_launch(void* const* d_in, const int* in_sizes, int n_in,
                              void* d_out, int out_size, void* d_ws, size_t ws_size,
                              hipStream_t stream) {
    const float* genes3 = (const float*)d_in[0];
    const float* genes2 = (const float*)d_in[1];
    const float* genes1 = (const float*)d_in[2];
    const float* genes0 = (const float*)d_in[3];
    const float* W3  = (const float*)d_in[4];
    const float* g3  = (const float*)d_in[6];
    const float* be3 = (const float*)d_in[7];
    const float* W2  = (const float*)d_in[8];
    const float* g2  = (const float*)d_in[10];
    const float* be2 = (const float*)d_in[11];
    const float* W1  = (const float*)d_in[12];
    const float* g1  = (const float*)d_in[14];
    const float* be1 = (const float*)d_in[15];
    const float* W0  = (const float*)d_in[16];
    const float* g0  = (const float*)d_in[18];
    const float* be0 = (const float*)d_in[19];
    const float* hw0 = (const float*)d_in[20];
    const float* hb0 = (const float*)d_in[21];

    char* wsb = (char*)d_ws;
    u64* gTb3 = (u64*)(wsb + OFF_GTB3);
    u64* gTb2 = (u64*)(wsb + OFF_GTB2);
    u64* gTb1 = (u64*)(wsb + OFF_GTB1);
    __half* h2  = (__half*)(wsb + OFF_H2B);
    __half* h1  = (__half*)(wsb + OFF_H1B);
    float*  z0p = (float*)(wsb + OFF_Z0B);

    // total rows = (2048+512+128)*256 = 688128; 32 rows per block
    k_pack_all<<<688128 / 32, 256, 0, stream>>>(genes3, genes2, genes1,
                                                gTb3, gTb2, gTb1);
    k_gemm32<<<T2_, 256, 0, stream>>>(gTb3, gTb2, W3, g3, be3,
                                      W2, g2, be2, h2);
    k_gemm<T1_, 4><<<T1_, 256, 0, stream>>>(h2, gTb1, W1, g1, be1, h1);
    k_stage0a<<<B_ * 4, 256, 0, stream>>>(h1, genes0, W0, z0p);
    k_stage0b<<<1, 256, 0, stream>>>(z0p, g0, be0, hw0, hb0, (float*)d_out);
}